// Round 6
// baseline (8240.298 us; speedup 1.0000x reference)
//
#include <hip/hip_runtime.h>

typedef unsigned short u16;

#define B_   8
#define CH   64
#define HW   2304
#define L2E  1.4426950408889634f

// ---- workspace byte offsets ----
#define OFF_XLC   0u          // bf16 [8][64][2304] channel-major
#define OFF_XRC   2359296u
#define OFF_XLT   4718592u    // bf16 [8][2304][64] position-major
#define OFF_XRT   7077888u
#define OFF_B1    9437184u    // f32  [8][64][2304]
#define OFF_B2    14155776u
#define OFF_RS2   18874368u   // f32  [8][2304]  1/S2[n]
// total 18948096 bytes

__device__ __forceinline__ float bf2f(u16 u){
  union { unsigned int i; float f; } v; v.i = ((unsigned int)u) << 16; return v.f;
}
__device__ __forceinline__ u16 f2bf(float f){
  union { float f; unsigned int i; } v; v.f = f;
  unsigned int r = v.i + 0x7FFFu + ((v.i >> 16) & 1u);
  return (u16)(r >> 16);
}

// ---------------- K1: xL/xR = W[64x128] @ concat(x_h,x_l) + b ----------------
// one thread per (p, o); raw f32 weights, no pre-transpose
// grid (9, 64, 16): p = bx*256+t, o = by, (b,side) = (bz>>1, bz&1)
__global__ __launch_bounds__(256) void k_proj(
    const float* xlh, const float* xll, const float* xrh, const float* xrl,
    const float* wLl, const float* bLl, const float* wRr, const float* bRr,
    char* ws)
{
  int p = blockIdx.x*256 + threadIdx.x;
  int o = blockIdx.y;
  int b = blockIdx.z >> 1, side = blockIdx.z & 1;
  const float* xh = (side ? xrh : xlh) + (size_t)b*CH*HW;
  const float* xl = (side ? xrl : xll) + (size_t)b*CH*HW;
  const float* w  = (side ? wRr : wLl) + (size_t)o*128;
  float acc = (side ? bRr : bLl)[o];
  #pragma unroll 8
  for (int c = 0; c < 64; ++c) acc = fmaf(w[c],    xh[(size_t)c*HW + p], acc);
  #pragma unroll 8
  for (int c = 0; c < 64; ++c) acc = fmaf(w[64+c], xl[(size_t)c*HW + p], acc);
  u16 v = f2bf(acc);
  u16* xc = (u16*)(ws + (side ? OFF_XRC : OFF_XLC)) + (size_t)b*CH*HW;
  u16* xt = (u16*)(ws + (side ? OFF_XRT : OFF_XLT)) + (size_t)b*HW*CH;
  xc[(size_t)o*HW + p] = v;
  xt[(size_t)p*CH + o] = v;
}

// ---------------- K2: S2[n] = sum_m exp(aff[n][m]) , store 1/S2 ----------------
// wave per (b, n); lane = channel c; butterfly-reduced 64-dot per m
// grid (576, 8), 4 waves/block
__global__ __launch_bounds__(256) void k_s2(char* ws)
{
  int wv = threadIdx.x >> 6;
  int c  = threadIdx.x & 63;
  int n  = blockIdx.x*4 + wv;
  int b  = blockIdx.y;
  const u16* xl = (const u16*)(ws + OFF_XLT) + (size_t)b*HW*CH;
  const u16* xr = (const u16*)(ws + OFF_XRT) + (size_t)b*HW*CH;
  float xlc = bf2f(xl[(size_t)n*CH + c]);     // xL[c][n] held in lane c
  float s = 0.f;
  for (int m = 0; m < HW; ++m){
    float t = xlc * bf2f(xr[(size_t)m*CH + c]);
    #pragma unroll
    for (int k = 1; k < 64; k <<= 1) t += __shfl_xor(t, k, 64);
    s += exp2f(t * L2E);                      // aff[n][m]; all lanes identical
  }
  if (c == 0) ((float*)(ws + OFF_RS2))[b*HW + n] = 1.0f / s;
}

// ---------------- K3: per-m row pass -> b1[:, m], b2[:, m] ----------------
// wave per (b, m). Pass 1: aff[n][m] for all n -> e stored in LDS, S1 summed.
// Pass 2: b1[c][m] = (sum_n xL[c][n]*e[n]) / S1 ; b2[c][m] = sum_n xR[c][n]*rs2[n]*e[n]
// grid (576, 8), 4 waves/block
__global__ __launch_bounds__(256) void k_b(char* ws)
{
  __shared__ float eb[4][HW];                 // 36864 B
  int wv = threadIdx.x >> 6;
  int c  = threadIdx.x & 63;
  int m  = blockIdx.x*4 + wv;
  int b  = blockIdx.y;
  const u16* xl = (const u16*)(ws + OFF_XLT) + (size_t)b*HW*CH;
  const u16* xr = (const u16*)(ws + OFF_XRT) + (size_t)b*HW*CH;
  const float* rs2 = (const float*)(ws + OFF_RS2) + b*HW;
  float xrc = bf2f(xr[(size_t)m*CH + c]);     // xR[c][m] in lane c
  float s1 = 0.f;
  for (int n = 0; n < HW; ++n){
    float t = xrc * bf2f(xl[(size_t)n*CH + c]);
    #pragma unroll
    for (int k = 1; k < 64; k <<= 1) t += __shfl_xor(t, k, 64);
    float e = exp2f(t * L2E);                 // exp(aff[n][m]); all lanes identical
    s1 += e;
    if (c == 0) eb[wv][n] = e;
  }
  float rs1 = 1.0f / s1;
  float a1acc = 0.f, a2acc = 0.f;
  for (int n = 0; n < HW; ++n){
    float e = eb[wv][n];
    a1acc = fmaf(bf2f(xl[(size_t)n*CH + c]), e, a1acc);
    a2acc = fmaf(bf2f(xr[(size_t)n*CH + c]) * rs2[n], e, a2acc);
  }
  float* B1 = (float*)(ws + OFF_B1) + (size_t)b*CH*HW;
  float* B2 = (float*)(ws + OFF_B2) + (size_t)b*CH*HW;
  B1[(size_t)c*HW + m] = a1acc * rs1;
  B2[(size_t)c*HW + m] = a2acc;
}

// ---------------- K4: gate + output convs (raw f32 weights), f32 OUTPUT ----------------
// grid (36, 2, 8): p-tile of 64, side, batch
__global__ __launch_bounds__(256) void k_out(
    char* ws,
    const float* gwL, const float* gbL, const float* gwR, const float* gbR,
    const float* wLo, const float* bLoi, const float* wRo, const float* bRoi,
    float* out)
{
  __shared__ float xT[64][64];
  __shared__ float bT[64][64];
  __shared__ float gpart[4][64];
  __shared__ float gLds[64];
  int t = threadIdx.x;
  int p0 = blockIdx.x*64;
  int side = blockIdx.y;
  int b = blockIdx.z;
  const float* braw = (const float*)(ws + (side ? OFF_B2 : OFF_B1)) + (size_t)b*CH*HW;
  const u16*   xc   = (const u16*)(ws + (side ? OFF_XRC : OFF_XLC)) + (size_t)b*CH*HW;
  const float* w    = side ? wRo : wLo;
  const float* gw   = side ? gwR : gwL;
  float        gb   = side ? gbR[0] : gbL[0];
  const float* bias = side ? bRoi : bLoi;

  #pragma unroll
  for (int i=0;i<16;i++){
    int flat = i*256 + t;
    int c = flat >> 6, pl = flat & 63;
    bT[c][pl] = braw[(size_t)c*HW + p0 + pl];
    xT[c][pl] = bf2f(xc[(size_t)c*HW + p0 + pl]);
  }
  __syncthreads();
  {
    int q = t >> 6, pl = t & 63;
    float a = 0.f;
    #pragma unroll
    for (int c = 0; c < 16; c++) a = fmaf(gw[16*q + c], bT[16*q + c][pl], a);
    gpart[q][pl] = a;
  }
  __syncthreads();
  if (t < 64){
    float x = gpart[0][t]+gpart[1][t]+gpart[2][t]+gpart[3][t] + gb;
    gLds[t] = 1.0f/(1.0f + exp2f(-x*L2E));    // sigmoid
  }
  __syncthreads();
  #pragma unroll
  for (int i=0;i<16;i++){
    int flat = i*256 + t;
    int c = flat >> 6, pl = flat & 63;
    bT[c][pl] *= gLds[pl];
  }
  __syncthreads();
  int wv = t >> 6;
  int lane = t & 63;
  float* outp = out + ((size_t)side*B_ + b)*CH*HW;
  for (int oi=0; oi<16; oi++){
    int o = wv*16 + oi;
    float a = bias[o];
    #pragma unroll 8
    for (int c=0;c<64;c++){
      a = fmaf(w[o*128 + c],      xT[c][lane], a);
      a = fmaf(w[o*128 + 64 + c], bT[c][lane], a);
    }
    outp[(size_t)o*HW + p0 + lane] = a;   // f32 store — the one variable changed
  }
}

extern "C" void kernel_launch(void* const* d_in, const int* in_sizes, int n_in,
                              void* d_out, int out_size, void* d_ws, size_t ws_size,
                              hipStream_t stream)
{
  char* ws = (char*)d_ws;
  k_proj<<<dim3(9,64,16), 256, 0, stream>>>(
      (const float*)d_in[0], (const float*)d_in[1],
      (const float*)d_in[2], (const float*)d_in[3],
      (const float*)d_in[4], (const float*)d_in[5],
      (const float*)d_in[6], (const float*)d_in[7], ws);
  k_s2 <<<dim3(576,8), 256, 0, stream>>>(ws);
  k_b  <<<dim3(576,8), 256, 0, stream>>>(ws);
  k_out<<<dim3(36,2,8), 256, 0, stream>>>(
      ws,
      (const float*)d_in[8],  (const float*)d_in[9],
      (const float*)d_in[10], (const float*)d_in[11],
      (const float*)d_in[12], (const float*)d_in[13],
      (const float*)d_in[14], (const float*)d_in[15],
      (float*)d_out);
}

// Round 7
// 390.251 us; speedup vs baseline: 21.1154x; 21.1154x over previous
//
#include <hip/hip_runtime.h>

typedef unsigned short u16;
typedef __bf16 bf16_t;
typedef bf16_t bf16x8 __attribute__((ext_vector_type(8)));
typedef float f32x4 __attribute__((ext_vector_type(4)));

#define B_   8
#define CH   64
#define HW   2304
#define L2E  1.4426950408889634f

// ---- workspace byte offsets ----
#define OFF_XLC   0u          // bf16 [8][64][2304] channel-major
#define OFF_XRC   2359296u
#define OFF_XLT   4718592u    // bf16 [8][2304][64] position-major
#define OFF_XRT   7077888u
#define OFF_XRS   9437184u    // bf16 [8][64][2304] xRc * recipS2[n]
#define OFF_B1    11796480u   // f32  [8][64][2304]
#define OFF_B2    16515072u
#define OFF_RS1   21233664u   // f32 [8][2304]  1/S1[m]
#define OFF_RS2   21307392u   // f32 [8][2304]  1/S2[n]
// total 21381120 bytes

__device__ __forceinline__ float bf2f(u16 u){
  union { unsigned int i; float f; } v; v.i = ((unsigned int)u) << 16; return v.f;
}
__device__ __forceinline__ u16 f2bf(float f){
  union { float f; unsigned int i; } v; v.f = f;
  unsigned int r = v.i + 0x7FFFu + ((v.i >> 16) & 1u);
  return (u16)(r >> 16);
}

// ---------------- K1: xL/xR = W[64x128] @ concat(x_h,x_l) + b ----------------
// thread per p, 32 outputs each; raw f32 weights (lane-uniform -> scalar loads)
// grid (9, 2, 16): p = bx*256+t, o0 = by*32, (b,side) = (bz>>1, bz&1)
__global__ __launch_bounds__(256) void k_proj(
    const float* xlh, const float* xll, const float* xrh, const float* xrl,
    const float* wLl, const float* bLl, const float* wRr, const float* bRr,
    char* ws)
{
  int p  = blockIdx.x*256 + threadIdx.x;
  int o0 = blockIdx.y*32;
  int b  = blockIdx.z >> 1, side = blockIdx.z & 1;
  const float* xh = (side ? xrh : xlh) + (size_t)b*CH*HW;
  const float* xl = (side ? xrl : xll) + (size_t)b*CH*HW;
  const float* w  = (side ? wRr : wLl);
  const float* bi = (side ? bRr : bLl);

  float acc[32];
  #pragma unroll
  for (int j=0;j<32;j++) acc[j] = bi[o0+j];
  for (int c=0;c<64;c++){
    float xv = xh[(size_t)c*HW + p];
    #pragma unroll
    for (int j=0;j<32;j++) acc[j] = fmaf(w[(size_t)(o0+j)*128 + c], xv, acc[j]);
  }
  for (int c=0;c<64;c++){
    float xv = xl[(size_t)c*HW + p];
    #pragma unroll
    for (int j=0;j<32;j++) acc[j] = fmaf(w[(size_t)(o0+j)*128 + 64 + c], xv, acc[j]);
  }
  u16* xc = (u16*)(ws + (side ? OFF_XRC : OFF_XLC)) + (size_t)b*CH*HW;
  u16* xt = (u16*)(ws + (side ? OFF_XRT : OFF_XLT)) + (size_t)b*HW*CH;
  unsigned int pk[16];
  #pragma unroll
  for (int j=0;j<16;j++){
    unsigned int lo16 = f2bf(acc[2*j]);
    unsigned int hi16 = f2bf(acc[2*j+1]);
    pk[j] = lo16 | (hi16 << 16);
    xc[(size_t)(o0+2*j  )*HW + p] = (u16)lo16;
    xc[(size_t)(o0+2*j+1)*HW + p] = (u16)hi16;
  }
  uint4* dst = (uint4*)&xt[(size_t)p*CH + o0];
  dst[0] = make_uint4(pk[0],pk[1],pk[2],pk[3]);
  dst[1] = make_uint4(pk[4],pk[5],pk[6],pk[7]);
  dst[2] = make_uint4(pk[8],pk[9],pk[10],pk[11]);
  dst[3] = make_uint4(pk[12],pk[13],pk[14],pk[15]);
}

// ---------------- K2: plain exp-sum stats (no max subtraction; |aff| small) ----------------
// z=0: X=xLt -> S2[n] = sum_m exp(aff[n,m]);  z=1: X=xRt -> S1[m] = sum_n exp(aff[n,m])
// stores RECIPROCAL 1/S as f32
__global__ __launch_bounds__(256) void k_stats(char* ws)
{
  const u16* xLt = (const u16*)(ws + OFF_XLT);
  const u16* xRt = (const u16*)(ws + OFF_XRT);
  int z = blockIdx.z, b = blockIdx.y;
  const u16* X = (z ? xRt : xLt) + (size_t)b*HW*CH;
  const u16* Y = (z ? xLt : xRt) + (size_t)b*HW*CH;
  float* out = (float*)(ws + (z ? OFF_RS1 : OFF_RS2)) + b*HW;

  int lane = threadIdx.x & 63;
  int wv   = __builtin_amdgcn_readfirstlane(threadIdx.x >> 6);
  int lo = lane & 15, g = lane >> 4;
  int r0 = blockIdx.x*64 + wv*16;

  bf16x8 a0 = *(const bf16x8*)&X[(size_t)(r0+lo)*CH + 8*g];
  bf16x8 a1 = *(const bf16x8*)&X[(size_t)(r0+lo)*CH + 32 + 8*g];

  float s[4] = {0.f, 0.f, 0.f, 0.f};

  for (int j0 = 0; j0 < HW; j0 += 16){
    bf16x8 b0 = *(const bf16x8*)&Y[(size_t)(j0+lo)*CH + 8*g];
    bf16x8 b1 = *(const bf16x8*)&Y[(size_t)(j0+lo)*CH + 32 + 8*g];
    f32x4 z4 = {0.f,0.f,0.f,0.f};
    f32x4 d = __builtin_amdgcn_mfma_f32_16x16x32_bf16(a0, b0, z4, 0,0,0);
    d = __builtin_amdgcn_mfma_f32_16x16x32_bf16(a1, b1, d, 0,0,0);
    #pragma unroll
    for (int r=0;r<4;r++) s[r] += exp2f(d[r]*L2E);
  }
  #pragma unroll
  for (int mask = 1; mask < 16; mask <<= 1){
    #pragma unroll
    for (int r=0;r<4;r++) s[r] += __shfl_xor(s[r], mask, 64);
  }
  if (lo == 0){
    #pragma unroll
    for (int r=0;r<4;r++) out[r0 + 4*g + r] = 1.0f / s[r];
  }
}

// ---------------- K2b: xRs[c][n] = xRc[c][n] * recipS2[n] ----------------
__global__ __launch_bounds__(256) void k_scale(char* ws)
{
  int n = blockIdx.x*256 + threadIdx.x;
  int c = blockIdx.y, b = blockIdx.z;
  const u16* xrc = (const u16*)(ws + OFF_XRC) + (size_t)b*CH*HW;
  const float* rs2 = (const float*)(ws + OFF_RS2) + b*HW;
  u16* xrs = (u16*)(ws + OFF_XRS) + (size_t)b*CH*HW;
  xrs[(size_t)c*HW + n] = f2bf(bf2f(xrc[(size_t)c*HW + n]) * rs2[n]);
}

// ---------------- K3: fused aff->P (in-register) -> b1^T/b2^T, full n-range ----------------
// Permuted A-row trick: QK^T A-rows loaded at row n0 + 8*(lo>>2) + (lo&3) (+4)
// so lane(lo,g) holds P[m0+lo][n0+8g+j], j=0..7 -- a ready A-fragment for
// b^T[m][c] = sum_n P[m][n] * xc[c][n]  (B = channel-major rows).
// grid (36, 8): m0 = (bx*4+wv)*16; z-split removed -> direct stores, no atomics
__global__ __launch_bounds__(256) void k_attn(char* ws)
{
  int b    = blockIdx.y;
  int lane = threadIdx.x & 63;
  int wv   = __builtin_amdgcn_readfirstlane(threadIdx.x >> 6);
  int lo = lane & 15, g = lane >> 4;
  int m0 = (blockIdx.x*4 + wv)*16;

  const u16* XLt = (const u16*)(ws + OFF_XLT) + (size_t)b*HW*CH;
  const u16* XRt = (const u16*)(ws + OFF_XRT) + (size_t)b*HW*CH;
  const u16* XLc = (const u16*)(ws + OFF_XLC) + (size_t)b*CH*HW;
  const u16* XRs = (const u16*)(ws + OFF_XRS) + (size_t)b*CH*HW;
  const float* rs1 = (const float*)(ws + OFF_RS1) + b*HW;

  float r1 = rs1[m0 + lo];                 // 1/S1[m] for this lane's m

  bf16x8 fm0 = *(const bf16x8*)&XRt[(size_t)(m0+lo)*CH + 8*g];
  bf16x8 fm1 = *(const bf16x8*)&XRt[(size_t)(m0+lo)*CH + 32 + 8*g];

  int pr = ((lo >> 2) << 3) + (lo & 3);    // {0..3,8..11,16..19,24..27}

  f32x4 acc1[4], acc2[4];
  #pragma unroll
  for (int ct=0;ct<4;ct++){ acc1[ct] = (f32x4){0.f,0.f,0.f,0.f}; acc2[ct] = (f32x4){0.f,0.f,0.f,0.f}; }

  for (int n0 = 0; n0 < HW; n0 += 32){
    bf16x8 fa00 = *(const bf16x8*)&XLt[(size_t)(n0+pr  )*CH +      8*g];
    bf16x8 fa01 = *(const bf16x8*)&XLt[(size_t)(n0+pr  )*CH + 32 + 8*g];
    bf16x8 fa10 = *(const bf16x8*)&XLt[(size_t)(n0+pr+4)*CH +      8*g];
    bf16x8 fa11 = *(const bf16x8*)&XLt[(size_t)(n0+pr+4)*CH + 32 + 8*g];
    f32x4 z4 = {0.f,0.f,0.f,0.f};
    f32x4 d0 = __builtin_amdgcn_mfma_f32_16x16x32_bf16(fa00, fm0, z4, 0,0,0);
    d0 = __builtin_amdgcn_mfma_f32_16x16x32_bf16(fa01, fm1, d0, 0,0,0);
    f32x4 d1 = __builtin_amdgcn_mfma_f32_16x16x32_bf16(fa10, fm0, z4, 0,0,0);
    d1 = __builtin_amdgcn_mfma_f32_16x16x32_bf16(fa11, fm1, d1, 0,0,0);

    // lane(lo,g): d0[r] = aff[n0+8g+r][m0+lo], d1[r] = aff[n0+8g+4+r][m0+lo]
    bf16x8 pa1, pa2;
    #pragma unroll
    for (int r=0;r<4;r++){
      float e0 = exp2f(d0[r]*L2E);
      float e1 = exp2f(d1[r]*L2E);
      pa1[r]   = (bf16_t)(e0 * r1);   // a1[n][m] normalized per-m
      pa1[r+4] = (bf16_t)(e1 * r1);
      pa2[r]   = (bf16_t)e0;          // exp(aff); 1/S2[n] folded into XRs
      pa2[r+4] = (bf16_t)e1;
    }
    #pragma unroll
    for (int ct=0; ct<4; ct++){
      bf16x8 bL = *(const bf16x8*)&XLc[(size_t)(16*ct+lo)*HW + n0 + 8*g];
      acc1[ct] = __builtin_amdgcn_mfma_f32_16x16x32_bf16(pa1, bL, acc1[ct], 0,0,0);
      bf16x8 bR = *(const bf16x8*)&XRs[(size_t)(16*ct+lo)*HW + n0 + 8*g];
      acc2[ct] = __builtin_amdgcn_mfma_f32_16x16x32_bf16(pa2, bR, acc2[ct], 0,0,0);
    }
  }
  float* B1 = (float*)(ws + OFF_B1) + (size_t)b*CH*HW;
  float* B2 = (float*)(ws + OFF_B2) + (size_t)b*CH*HW;
  #pragma unroll
  for (int ct=0;ct<4;ct++){
    int c = 16*ct + lo;
    #pragma unroll
    for (int r=0;r<4;r++){
      int m = m0 + 4*g + r;
      B1[(size_t)c*HW + m] = acc1[ct][r];
      B2[(size_t)c*HW + m] = acc2[ct][r];
    }
  }
}

// ---------------- K4: gate + output convs (raw f32 weights), f32 OUTPUT ----------------
// grid (36, 2, 8): p-tile of 64, side, batch
__global__ __launch_bounds__(256) void k_out(
    char* ws,
    const float* gwL, const float* gbL, const float* gwR, const float* gbR,
    const float* wLo, const float* bLoi, const float* wRo, const float* bRoi,
    float* out)
{
  __shared__ float xT[64][64];
  __shared__ float bT[64][64];
  __shared__ float gpart[4][64];
  __shared__ float gLds[64];
  int t = threadIdx.x;
  int p0 = blockIdx.x*64;
  int side = blockIdx.y;
  int b = blockIdx.z;
  const float* braw = (const float*)(ws + (side ? OFF_B2 : OFF_B1)) + (size_t)b*CH*HW;
  const u16*   xc   = (const u16*)(ws + (side ? OFF_XRC : OFF_XLC)) + (size_t)b*CH*HW;
  const float* w    = side ? wRo : wLo;
  const float* gw   = side ? gwR : gwL;
  float        gb   = side ? gbR[0] : gbL[0];
  const float* bias = side ? bRoi : bLoi;

  #pragma unroll
  for (int i=0;i<16;i++){
    int flat = i*256 + t;
    int c = flat >> 6, pl = flat & 63;
    bT[c][pl] = braw[(size_t)c*HW + p0 + pl];
    xT[c][pl] = bf2f(xc[(size_t)c*HW + p0 + pl]);
  }
  __syncthreads();
  {
    int q = t >> 6, pl = t & 63;
    float a = 0.f;
    #pragma unroll
    for (int c = 0; c < 16; c++) a = fmaf(gw[16*q + c], bT[16*q + c][pl], a);
    gpart[q][pl] = a;
  }
  __syncthreads();
  if (t < 64){
    float x = gpart[0][t]+gpart[1][t]+gpart[2][t]+gpart[3][t] + gb;
    gLds[t] = 1.0f/(1.0f + exp2f(-x*L2E));    // sigmoid
  }
  __syncthreads();
  #pragma unroll
  for (int i=0;i<16;i++){
    int flat = i*256 + t;
    int c = flat >> 6, pl = flat & 63;
    bT[c][pl] *= gLds[pl];
  }
  __syncthreads();
  int wv = t >> 6;
  int lane = t & 63;
  float* outp = out + ((size_t)side*B_ + b)*CH*HW;
  for (int oi=0; oi<16; oi++){
    int o = wv*16 + oi;
    float a = bias[o];
    #pragma unroll 8
    for (int c=0;c<64;c++){
      a = fmaf(w[o*128 + c],      xT[c][lane], a);
      a = fmaf(w[o*128 + 64 + c], bT[c][lane], a);
    }
    outp[(size_t)o*HW + p0 + lane] = a;
  }
}

extern "C" void kernel_launch(void* const* d_in, const int* in_sizes, int n_in,
                              void* d_out, int out_size, void* d_ws, size_t ws_size,
                              hipStream_t stream)
{
  char* ws = (char*)d_ws;
  k_proj <<<dim3(9,2,16), 256, 0, stream>>>(
      (const float*)d_in[0], (const float*)d_in[1],
      (const float*)d_in[2], (const float*)d_in[3],
      (const float*)d_in[4], (const float*)d_in[5],
      (const float*)d_in[6], (const float*)d_in[7], ws);
  k_stats<<<dim3(36,8,2), 256, 0, stream>>>(ws);
  k_scale<<<dim3(9,64,8), 256, 0, stream>>>(ws);
  k_attn <<<dim3(36,8), 256, 0, stream>>>(ws);
  k_out  <<<dim3(36,2,8), 256, 0, stream>>>(
      ws,
      (const float*)d_in[8],  (const float*)d_in[9],
      (const float*)d_in[10], (const float*)d_in[11],
      (const float*)d_in[12], (const float*)d_in[13],
      (const float*)d_in[14], (const float*)d_in[15],
      (float*)d_out);
}

// Round 8
// 302.198 us; speedup vs baseline: 27.2679x; 1.2914x over previous
//
#include <hip/hip_runtime.h>

typedef unsigned short u16;
typedef __bf16 bf16_t;
typedef bf16_t bf16x8 __attribute__((ext_vector_type(8)));
typedef float f32x4 __attribute__((ext_vector_type(4)));

#define B_   8
#define CH   64
#define HW   2304
#define L2E  1.4426950408889634f

// ---- workspace byte offsets ----
#define OFF_XLC   0u          // bf16 [8][64][2304] channel-major
#define OFF_XRC   2359296u
#define OFF_XLT   4718592u    // bf16 [8][2304][64] position-major
#define OFF_XRT   7077888u
#define OFF_XRS   9437184u    // bf16 [8][64][2304] xRc * recipS2[n]
#define OFF_B1    11796480u   // f32  [8][64][2304]
#define OFF_B2    16515072u
#define OFF_RS1   21233664u   // f32 [8][2304]  1/S1[m]
#define OFF_RS2   21307392u   // f32 [8][2304]  1/S2[n]
// total 21381120 bytes

__device__ __forceinline__ float bf2f(u16 u){
  union { unsigned int i; float f; } v; v.i = ((unsigned int)u) << 16; return v.f;
}
__device__ __forceinline__ u16 f2bf(float f){
  union { float f; unsigned int i; } v; v.f = f;
  unsigned int r = v.i + 0x7FFFu + ((v.i >> 16) & 1u);
  return (u16)(r >> 16);
}

// ---------------- K1: xL/xR = W[64x128] @ concat(x_h,x_l) + b ----------------
// grid (9, 2, 16): p = bx*256+t, o0 = by*32, (b,side) = (bz>>1, bz&1)
__global__ __launch_bounds__(256) void k_proj(
    const float* xlh, const float* xll, const float* xrh, const float* xrl,
    const float* wLl, const float* bLl, const float* wRr, const float* bRr,
    char* ws)
{
  int p  = blockIdx.x*256 + threadIdx.x;
  int o0 = blockIdx.y*32;
  int b  = blockIdx.z >> 1, side = blockIdx.z & 1;
  const float* xh = (side ? xrh : xlh) + (size_t)b*CH*HW;
  const float* xl = (side ? xrl : xll) + (size_t)b*CH*HW;
  const float* w  = (side ? wRr : wLl);
  const float* bi = (side ? bRr : bLl);

  float acc[32];
  #pragma unroll
  for (int j=0;j<32;j++) acc[j] = bi[o0+j];
  for (int c=0;c<64;c++){
    float xv = xh[(size_t)c*HW + p];
    #pragma unroll
    for (int j=0;j<32;j++) acc[j] = fmaf(w[(size_t)(o0+j)*128 + c], xv, acc[j]);
  }
  for (int c=0;c<64;c++){
    float xv = xl[(size_t)c*HW + p];
    #pragma unroll
    for (int j=0;j<32;j++) acc[j] = fmaf(w[(size_t)(o0+j)*128 + 64 + c], xv, acc[j]);
  }
  u16* xc = (u16*)(ws + (side ? OFF_XRC : OFF_XLC)) + (size_t)b*CH*HW;
  u16* xt = (u16*)(ws + (side ? OFF_XRT : OFF_XLT)) + (size_t)b*HW*CH;
  unsigned int pk[16];
  #pragma unroll
  for (int j=0;j<16;j++){
    unsigned int lo16 = f2bf(acc[2*j]);
    unsigned int hi16 = f2bf(acc[2*j+1]);
    pk[j] = lo16 | (hi16 << 16);
    xc[(size_t)(o0+2*j  )*HW + p] = (u16)lo16;
    xc[(size_t)(o0+2*j+1)*HW + p] = (u16)hi16;
  }
  uint4* dst = (uint4*)&xt[(size_t)p*CH + o0];
  dst[0] = make_uint4(pk[0],pk[1],pk[2],pk[3]);
  dst[1] = make_uint4(pk[4],pk[5],pk[6],pk[7]);
  dst[2] = make_uint4(pk[8],pk[9],pk[10],pk[11]);
  dst[3] = make_uint4(pk[12],pk[13],pk[14],pk[15]);
}

// ---------------- K2: exp-sum stats, col-split across the 4 waves ----------------
// grid (144, 8, 2): block = 16 rows; wave wv handles col-quarter [wv*576,(wv+1)*576)
// z=0: X=xLt -> 1/S2[n];  z=1: X=xRt -> 1/S1[m]
__global__ __launch_bounds__(256) void k_stats(char* ws)
{
  __shared__ float part[4][4][4];
  const u16* xLt = (const u16*)(ws + OFF_XLT);
  const u16* xRt = (const u16*)(ws + OFF_XRT);
  int z = blockIdx.z, b = blockIdx.y;
  const u16* X = (z ? xRt : xLt) + (size_t)b*HW*CH;
  const u16* Y = (z ? xLt : xRt) + (size_t)b*HW*CH;
  float* out = (float*)(ws + (z ? OFF_RS1 : OFF_RS2)) + b*HW;

  int lane = threadIdx.x & 63;
  int wv   = __builtin_amdgcn_readfirstlane(threadIdx.x >> 6);
  int lo = lane & 15, g = lane >> 4;
  int r0 = blockIdx.x*16;

  bf16x8 a0 = *(const bf16x8*)&X[(size_t)(r0+lo)*CH + 8*g];
  bf16x8 a1 = *(const bf16x8*)&X[(size_t)(r0+lo)*CH + 32 + 8*g];

  float s[4] = {0.f, 0.f, 0.f, 0.f};
  int jbeg = wv * (HW/4);
  for (int i = 0; i < 18; ++i){
    int j0 = jbeg + i*16;
    bf16x8 b0 = *(const bf16x8*)&Y[(size_t)(j0+lo)*CH + 8*g];
    bf16x8 b1 = *(const bf16x8*)&Y[(size_t)(j0+lo)*CH + 32 + 8*g];
    f32x4 z4 = {0.f,0.f,0.f,0.f};
    f32x4 d = __builtin_amdgcn_mfma_f32_16x16x32_bf16(a0, b0, z4, 0,0,0);
    d = __builtin_amdgcn_mfma_f32_16x16x32_bf16(a1, b1, d, 0,0,0);
    #pragma unroll
    for (int r=0;r<4;r++) s[r] += exp2f(d[r]*L2E);
  }
  // wait: quarter = 576 cols -> 36 iters of 16
  for (int i = 18; i < 36; ++i){
    int j0 = jbeg + i*16;
    bf16x8 b0 = *(const bf16x8*)&Y[(size_t)(j0+lo)*CH + 8*g];
    bf16x8 b1 = *(const bf16x8*)&Y[(size_t)(j0+lo)*CH + 32 + 8*g];
    f32x4 z4 = {0.f,0.f,0.f,0.f};
    f32x4 d = __builtin_amdgcn_mfma_f32_16x16x32_bf16(a0, b0, z4, 0,0,0);
    d = __builtin_amdgcn_mfma_f32_16x16x32_bf16(a1, b1, d, 0,0,0);
    #pragma unroll
    for (int r=0;r<4;r++) s[r] += exp2f(d[r]*L2E);
  }
  #pragma unroll
  for (int mask = 1; mask < 16; mask <<= 1){
    #pragma unroll
    for (int r=0;r<4;r++) s[r] += __shfl_xor(s[r], mask, 64);
  }
  if (lo == 0){
    #pragma unroll
    for (int r=0;r<4;r++) part[wv][g][r] = s[r];
  }
  __syncthreads();
  if (threadIdx.x < 16){
    int t = threadIdx.x;
    float sum = part[0][t>>2][t&3] + part[1][t>>2][t&3]
              + part[2][t>>2][t&3] + part[3][t>>2][t&3];
    out[r0 + t] = 1.0f / sum;
  }
}

// ---------------- K2b: xRs[c][n] = xRc[c][n] * recipS2[n] ----------------
__global__ __launch_bounds__(256) void k_scale(char* ws)
{
  int n = blockIdx.x*256 + threadIdx.x;
  int c = blockIdx.y, b = blockIdx.z;
  const u16* xrc = (const u16*)(ws + OFF_XRC) + (size_t)b*CH*HW;
  const float* rs2 = (const float*)(ws + OFF_RS2) + b*HW;
  u16* xrs = (u16*)(ws + OFF_XRS) + (size_t)b*CH*HW;
  xrs[(size_t)c*HW + n] = f2bf(bf2f(xrc[(size_t)c*HW + n]) * rs2[n]);
}

// ---------------- K3: fused aff->P -> b1^T/b2^T, n-split across 4 waves ----------------
// grid (144, 8): block = one 16-m tile; wave wv handles n-quarter; LDS tree-reduce.
// Permuted A-row trick: lane(lo,g) holds P[m0+lo][n0+8g+j] as a ready A-fragment.
__global__ __launch_bounds__(256, 4) void k_attn(char* ws)
{
  __shared__ float red[4][64][17];
  int b    = blockIdx.y;
  int lane = threadIdx.x & 63;
  int wv   = __builtin_amdgcn_readfirstlane(threadIdx.x >> 6);
  int lo = lane & 15, g = lane >> 4;
  int m0 = blockIdx.x * 16;

  const u16* XLt = (const u16*)(ws + OFF_XLT) + (size_t)b*HW*CH;
  const u16* XRt = (const u16*)(ws + OFF_XRT) + (size_t)b*HW*CH;
  const u16* XLc = (const u16*)(ws + OFF_XLC) + (size_t)b*CH*HW;
  const u16* XRs = (const u16*)(ws + OFF_XRS) + (size_t)b*CH*HW;
  const float* rs1 = (const float*)(ws + OFF_RS1) + b*HW;

  float r1 = rs1[m0 + lo];                 // 1/S1[m] for this lane's m

  bf16x8 fm0 = *(const bf16x8*)&XRt[(size_t)(m0+lo)*CH + 8*g];
  bf16x8 fm1 = *(const bf16x8*)&XRt[(size_t)(m0+lo)*CH + 32 + 8*g];

  int pr = ((lo >> 2) << 3) + (lo & 3);    // {0..3,8..11,16..19,24..27}

  f32x4 acc1[4], acc2[4];
  #pragma unroll
  for (int ct=0;ct<4;ct++){ acc1[ct] = (f32x4){0.f,0.f,0.f,0.f}; acc2[ct] = (f32x4){0.f,0.f,0.f,0.f}; }

  int nbeg = wv * (HW/4);
  for (int s = 0; s < 18; ++s){
    int n0 = nbeg + s*32;
    bf16x8 fa00 = *(const bf16x8*)&XLt[(size_t)(n0+pr  )*CH +      8*g];
    bf16x8 fa01 = *(const bf16x8*)&XLt[(size_t)(n0+pr  )*CH + 32 + 8*g];
    bf16x8 fa10 = *(const bf16x8*)&XLt[(size_t)(n0+pr+4)*CH +      8*g];
    bf16x8 fa11 = *(const bf16x8*)&XLt[(size_t)(n0+pr+4)*CH + 32 + 8*g];
    f32x4 z4 = {0.f,0.f,0.f,0.f};
    f32x4 d0 = __builtin_amdgcn_mfma_f32_16x16x32_bf16(fa00, fm0, z4, 0,0,0);
    d0 = __builtin_amdgcn_mfma_f32_16x16x32_bf16(fa01, fm1, d0, 0,0,0);
    f32x4 d1 = __builtin_amdgcn_mfma_f32_16x16x32_bf16(fa10, fm0, z4, 0,0,0);
    d1 = __builtin_amdgcn_mfma_f32_16x16x32_bf16(fa11, fm1, d1, 0,0,0);

    // lane(lo,g): d0[r] = aff[n0+8g+r][m0+lo], d1[r] = aff[n0+8g+4+r][m0+lo]
    bf16x8 pa1, pa2;
    #pragma unroll
    for (int r=0;r<4;r++){
      float e0 = exp2f(d0[r]*L2E);
      float e1 = exp2f(d1[r]*L2E);
      pa1[r]   = (bf16_t)(e0 * r1);   // a1[n][m] normalized per-m
      pa1[r+4] = (bf16_t)(e1 * r1);
      pa2[r]   = (bf16_t)e0;          // exp(aff); 1/S2[n] folded into XRs
      pa2[r+4] = (bf16_t)e1;
    }
    #pragma unroll
    for (int ct=0; ct<4; ct++){
      bf16x8 bL = *(const bf16x8*)&XLc[(size_t)(16*ct+lo)*HW + n0 + 8*g];
      acc1[ct] = __builtin_amdgcn_mfma_f32_16x16x32_bf16(pa1, bL, acc1[ct], 0,0,0);
      bf16x8 bR = *(const bf16x8*)&XRs[(size_t)(16*ct+lo)*HW + n0 + 8*g];
      acc2[ct] = __builtin_amdgcn_mfma_f32_16x16x32_bf16(pa2, bR, acc2[ct], 0,0,0);
    }
  }

  float* B1 = (float*)(ws + OFF_B1) + (size_t)b*CH*HW;
  float* B2 = (float*)(ws + OFF_B2) + (size_t)b*CH*HW;
  int rl = threadIdx.x & 63;          // reduce-phase lane
  int rv = threadIdx.x >> 6;          // reduce-phase v-base

  // phase A: reduce acc1 -> B1
  #pragma unroll
  for (int v=0; v<16; ++v) red[wv][lane][v] = acc1[v>>2][v&3];
  __syncthreads();
  #pragma unroll
  for (int k=0;k<4;k++){
    int v = rv + 4*k;
    float s = red[0][rl][v] + red[1][rl][v] + red[2][rl][v] + red[3][rl][v];
    int c = ((v>>2)<<4) + (rl & 15);
    int m = m0 + ((rl>>4)<<2) + (v&3);
    B1[(size_t)c*HW + m] = s;
  }
  __syncthreads();
  // phase B: reduce acc2 -> B2
  #pragma unroll
  for (int v=0; v<16; ++v) red[wv][lane][v] = acc2[v>>2][v&3];
  __syncthreads();
  #pragma unroll
  for (int k=0;k<4;k++){
    int v = rv + 4*k;
    float s = red[0][rl][v] + red[1][rl][v] + red[2][rl][v] + red[3][rl][v];
    int c = ((v>>2)<<4) + (rl & 15);
    int m = m0 + ((rl>>4)<<2) + (v&3);
    B2[(size_t)c*HW + m] = s;
  }
}

// ---------------- K4: gate + output convs (raw f32 weights), f32 OUTPUT ----------------
// grid (36, 2, 8): p-tile of 64, side, batch
__global__ __launch_bounds__(256) void k_out(
    char* ws,
    const float* gwL, const float* gbL, const float* gwR, const float* gbR,
    const float* wLo, const float* bLoi, const float* wRo, const float* bRoi,
    float* out)
{
  __shared__ float xT[64][64];
  __shared__ float bT[64][64];
  __shared__ float gpart[4][64];
  __shared__ float gLds[64];
  int t = threadIdx.x;
  int p0 = blockIdx.x*64;
  int side = blockIdx.y;
  int b = blockIdx.z;
  const float* braw = (const float*)(ws + (side ? OFF_B2 : OFF_B1)) + (size_t)b*CH*HW;
  const u16*   xc   = (const u16*)(ws + (side ? OFF_XRC : OFF_XLC)) + (size_t)b*CH*HW;
  const float* w    = side ? wRo : wLo;
  const float* gw   = side ? gwR : gwL;
  float        gb   = side ? gbR[0] : gbL[0];
  const float* bias = side ? bRoi : bLoi;

  #pragma unroll
  for (int i=0;i<16;i++){
    int flat = i*256 + t;
    int c = flat >> 6, pl = flat & 63;
    bT[c][pl] = braw[(size_t)c*HW + p0 + pl];
    xT[c][pl] = bf2f(xc[(size_t)c*HW + p0 + pl]);
  }
  __syncthreads();
  {
    int q = t >> 6, pl = t & 63;
    float a = 0.f;
    #pragma unroll
    for (int c = 0; c < 16; c++) a = fmaf(gw[16*q + c], bT[16*q + c][pl], a);
    gpart[q][pl] = a;
  }
  __syncthreads();
  if (t < 64){
    float x = gpart[0][t]+gpart[1][t]+gpart[2][t]+gpart[3][t] + gb;
    gLds[t] = 1.0f/(1.0f + exp2f(-x*L2E));    // sigmoid
  }
  __syncthreads();
  #pragma unroll
  for (int i=0;i<16;i++){
    int flat = i*256 + t;
    int c = flat >> 6, pl = flat & 63;
    bT[c][pl] *= gLds[pl];
  }
  __syncthreads();
  int wv = t >> 6;
  int lane = t & 63;
  float* outp = out + ((size_t)side*B_ + b)*CH*HW;
  for (int oi=0; oi<16; oi++){
    int o = wv*16 + oi;
    float a = bias[o];
    #pragma unroll 8
    for (int c=0;c<64;c++){
      a = fmaf(w[o*128 + c],      xT[c][lane], a);
      a = fmaf(w[o*128 + 64 + c], bT[c][lane], a);
    }
    outp[(size_t)o*HW + p0 + lane] = a;
  }
}

extern "C" void kernel_launch(void* const* d_in, const int* in_sizes, int n_in,
                              void* d_out, int out_size, void* d_ws, size_t ws_size,
                              hipStream_t stream)
{
  char* ws = (char*)d_ws;
  k_proj <<<dim3(9,2,16), 256, 0, stream>>>(
      (const float*)d_in[0], (const float*)d_in[1],
      (const float*)d_in[2], (const float*)d_in[3],
      (const float*)d_in[4], (const float*)d_in[5],
      (const float*)d_in[6], (const float*)d_in[7], ws);
  k_stats<<<dim3(144,8,2), 256, 0, stream>>>(ws);
  k_scale<<<dim3(9,64,8), 256, 0, stream>>>(ws);
  k_attn <<<dim3(144,8), 256, 0, stream>>>(ws);
  k_out  <<<dim3(36,2,8), 256, 0, stream>>>(
      ws,
      (const float*)d_in[8],  (const float*)d_in[9],
      (const float*)d_in[10], (const float*)d_in[11],
      (const float*)d_in[12], (const float*)d_in[13],
      (const float*)d_in[14], (const float*)d_in[15],
      (float*)d_out);
}

// Round 9
// 208.727 us; speedup vs baseline: 39.4788x; 1.4478x over previous
//
#include <hip/hip_runtime.h>

typedef unsigned short u16;
typedef __bf16 bf16_t;
typedef bf16_t bf16x8 __attribute__((ext_vector_type(8)));
typedef float f32x4 __attribute__((ext_vector_type(4)));

#define B_   8
#define CH   64
#define HW   2304
#define L2E  1.4426950408889634f

// ---- workspace byte offsets ----
#define OFF_XLC   0u          // bf16 [8][64][2304] channel-major
#define OFF_XRC   2359296u
#define OFF_XLT   4718592u    // bf16 [8][2304][64] position-major
#define OFF_XRT   7077888u
#define OFF_B1    11796480u   // f32  [8][64][2304]
#define OFF_B2    16515072u
#define OFF_RS2   21307392u   // f32 [8][2304]  1/S2[n]
// total <= 21381120 bytes (same footprint as round 8)

__device__ __forceinline__ float bf2f(u16 u){
  union { unsigned int i; float f; } v; v.i = ((unsigned int)u) << 16; return v.f;
}
__device__ __forceinline__ u16 f2bf(float f){
  union { float f; unsigned int i; } v; v.f = f;
  unsigned int r = v.i + 0x7FFFu + ((v.i >> 16) & 1u);
  return (u16)(r >> 16);
}

// ---------------- K1: xL/xR = W[64x128] @ concat(x_h,x_l) + b ----------------
// grid (9, 2, 16): p = bx*256+t, o0 = by*32, (b,side) = (bz>>1, bz&1)
__global__ __launch_bounds__(256) void k_proj(
    const float* xlh, const float* xll, const float* xrh, const float* xrl,
    const float* wLl, const float* bLl, const float* wRr, const float* bRr,
    char* ws)
{
  int p  = blockIdx.x*256 + threadIdx.x;
  int o0 = blockIdx.y*32;
  int b  = blockIdx.z >> 1, side = blockIdx.z & 1;
  const float* xh = (side ? xrh : xlh) + (size_t)b*CH*HW;
  const float* xl = (side ? xrl : xll) + (size_t)b*CH*HW;
  const float* w  = (side ? wRr : wLl);
  const float* bi = (side ? bRr : bLl);

  float acc[32];
  #pragma unroll
  for (int j=0;j<32;j++) acc[j] = bi[o0+j];
  for (int c=0;c<64;c++){
    float xv = xh[(size_t)c*HW + p];
    #pragma unroll
    for (int j=0;j<32;j++) acc[j] = fmaf(w[(size_t)(o0+j)*128 + c], xv, acc[j]);
  }
  for (int c=0;c<64;c++){
    float xv = xl[(size_t)c*HW + p];
    #pragma unroll
    for (int j=0;j<32;j++) acc[j] = fmaf(w[(size_t)(o0+j)*128 + 64 + c], xv, acc[j]);
  }
  u16* xc = (u16*)(ws + (side ? OFF_XRC : OFF_XLC)) + (size_t)b*CH*HW;
  u16* xt = (u16*)(ws + (side ? OFF_XRT : OFF_XLT)) + (size_t)b*HW*CH;
  unsigned int pk[16];
  #pragma unroll
  for (int j=0;j<16;j++){
    unsigned int lo16 = f2bf(acc[2*j]);
    unsigned int hi16 = f2bf(acc[2*j+1]);
    pk[j] = lo16 | (hi16 << 16);
    xc[(size_t)(o0+2*j  )*HW + p] = (u16)lo16;
    xc[(size_t)(o0+2*j+1)*HW + p] = (u16)hi16;
  }
  uint4* dst = (uint4*)&xt[(size_t)p*CH + o0];
  dst[0] = make_uint4(pk[0],pk[1],pk[2],pk[3]);
  dst[1] = make_uint4(pk[4],pk[5],pk[6],pk[7]);
  dst[2] = make_uint4(pk[8],pk[9],pk[10],pk[11]);
  dst[3] = make_uint4(pk[12],pk[13],pk[14],pk[15]);
}

// ---------------- K2: 1/S2[n] = 1/sum_m exp(aff[n,m]); 32 rows/block, prefetch ----------------
// grid (72, 8): r0 = bx*32; wave wv reduces its m-quarter; LDS cross-wave combine
__global__ __launch_bounds__(256) void k_stats(char* ws)
{
  __shared__ float part[4][2][4][4];
  int b = blockIdx.y;
  const u16* X = (const u16*)(ws + OFF_XLT) + (size_t)b*HW*CH;   // rows n
  const u16* Y = (const u16*)(ws + OFF_XRT) + (size_t)b*HW*CH;   // reduce over m
  float* out = (float*)(ws + OFF_RS2) + b*HW;

  int lane = threadIdx.x & 63;
  int wv   = __builtin_amdgcn_readfirstlane(threadIdx.x >> 6);
  int lo = lane & 15, g = lane >> 4;
  int r0 = blockIdx.x*32;

  bf16x8 aA0 = *(const bf16x8*)&X[(size_t)(r0+lo)*CH + 8*g];
  bf16x8 aA1 = *(const bf16x8*)&X[(size_t)(r0+lo)*CH + 32 + 8*g];
  bf16x8 aB0 = *(const bf16x8*)&X[(size_t)(r0+16+lo)*CH + 8*g];
  bf16x8 aB1 = *(const bf16x8*)&X[(size_t)(r0+16+lo)*CH + 32 + 8*g];

  float sA[4] = {0.f,0.f,0.f,0.f};
  float sB[4] = {0.f,0.f,0.f,0.f};
  int jbeg = wv * (HW/4);

  bf16x8 b0 = *(const bf16x8*)&Y[(size_t)(jbeg+lo)*CH + 8*g];
  bf16x8 b1 = *(const bf16x8*)&Y[(size_t)(jbeg+lo)*CH + 32 + 8*g];
  #pragma unroll 2
  for (int i = 0; i < 36; ++i){
    int jn = jbeg + ((i+1 < 36) ? (i+1)*16 : 0);
    bf16x8 nb0 = *(const bf16x8*)&Y[(size_t)(jn+lo)*CH + 8*g];
    bf16x8 nb1 = *(const bf16x8*)&Y[(size_t)(jn+lo)*CH + 32 + 8*g];
    f32x4 z4 = {0.f,0.f,0.f,0.f};
    f32x4 dA = __builtin_amdgcn_mfma_f32_16x16x32_bf16(aA0, b0, z4, 0,0,0);
    dA = __builtin_amdgcn_mfma_f32_16x16x32_bf16(aA1, b1, dA, 0,0,0);
    f32x4 dB = __builtin_amdgcn_mfma_f32_16x16x32_bf16(aB0, b0, z4, 0,0,0);
    dB = __builtin_amdgcn_mfma_f32_16x16x32_bf16(aB1, b1, dB, 0,0,0);
    #pragma unroll
    for (int r=0;r<4;r++){ sA[r] += exp2f(dA[r]*L2E); sB[r] += exp2f(dB[r]*L2E); }
    b0 = nb0; b1 = nb1;
  }
  #pragma unroll
  for (int mask = 1; mask < 16; mask <<= 1){
    #pragma unroll
    for (int r=0;r<4;r++){ sA[r] += __shfl_xor(sA[r], mask, 64); sB[r] += __shfl_xor(sB[r], mask, 64); }
  }
  if (lo == 0){
    #pragma unroll
    for (int r=0;r<4;r++){ part[wv][0][g][r] = sA[r]; part[wv][1][g][r] = sB[r]; }
  }
  __syncthreads();
  if (threadIdx.x < 32){
    int t = threadIdx.x;
    int half = t >> 4, gg = (t & 15) >> 2, rr = t & 3;
    float sum = part[0][half][gg][rr] + part[1][half][gg][rr]
              + part[2][half][gg][rr] + part[3][half][gg][rr];
    out[r0 + 16*half + 4*gg + rr] = 1.0f / sum;
  }
}

// ---------------- K3 helpers ----------------
__device__ __forceinline__ void attn_compute(
    const bf16x8& fa00, const bf16x8& fa01, const bf16x8& fa10, const bf16x8& fa11,
    const bf16x8& bL0, const bf16x8& bL1, const bf16x8& bL2, const bf16x8& bL3,
    const bf16x8& bR0, const bf16x8& bR1, const bf16x8& bR2, const bf16x8& bR3,
    const f32x4& r20, const f32x4& r21,
    const bf16x8& fmA0, const bf16x8& fmA1, const bf16x8& fmB0, const bf16x8& fmB1,
    f32x4 acc1A[4], f32x4 acc2A[4], f32x4 acc1B[4], f32x4 acc2B[4],
    float& s1A, float& s1B)
{
  f32x4 z4 = {0.f,0.f,0.f,0.f};
  f32x4 d0A = __builtin_amdgcn_mfma_f32_16x16x32_bf16(fa00, fmA0, z4, 0,0,0);
  d0A = __builtin_amdgcn_mfma_f32_16x16x32_bf16(fa01, fmA1, d0A, 0,0,0);
  f32x4 d1A = __builtin_amdgcn_mfma_f32_16x16x32_bf16(fa10, fmA0, z4, 0,0,0);
  d1A = __builtin_amdgcn_mfma_f32_16x16x32_bf16(fa11, fmA1, d1A, 0,0,0);
  f32x4 d0B = __builtin_amdgcn_mfma_f32_16x16x32_bf16(fa00, fmB0, z4, 0,0,0);
  d0B = __builtin_amdgcn_mfma_f32_16x16x32_bf16(fa01, fmB1, d0B, 0,0,0);
  f32x4 d1B = __builtin_amdgcn_mfma_f32_16x16x32_bf16(fa10, fmB0, z4, 0,0,0);
  d1B = __builtin_amdgcn_mfma_f32_16x16x32_bf16(fa11, fmB1, d1B, 0,0,0);

  bf16x8 pa1A, pa2A, pa1B, pa2B;
  #pragma unroll
  for (int r=0;r<4;r++){
    float e0 = exp2f(d0A[r]*L2E);
    float e1 = exp2f(d1A[r]*L2E);
    s1A += e0 + e1;
    pa1A[r]   = (bf16_t)e0;            // unnormalized; 1/S1 applied at writeout
    pa1A[r+4] = (bf16_t)e1;
    pa2A[r]   = (bf16_t)(e0 * r20[r]); // 1/S2[n] applied per-lane
    pa2A[r+4] = (bf16_t)(e1 * r21[r]);
    float f0 = exp2f(d0B[r]*L2E);
    float f1 = exp2f(d1B[r]*L2E);
    s1B += f0 + f1;
    pa1B[r]   = (bf16_t)f0;
    pa1B[r+4] = (bf16_t)f1;
    pa2B[r]   = (bf16_t)(f0 * r20[r]);
    pa2B[r+4] = (bf16_t)(f1 * r21[r]);
  }
  acc1A[0] = __builtin_amdgcn_mfma_f32_16x16x32_bf16(pa1A, bL0, acc1A[0], 0,0,0);
  acc1A[1] = __builtin_amdgcn_mfma_f32_16x16x32_bf16(pa1A, bL1, acc1A[1], 0,0,0);
  acc1A[2] = __builtin_amdgcn_mfma_f32_16x16x32_bf16(pa1A, bL2, acc1A[2], 0,0,0);
  acc1A[3] = __builtin_amdgcn_mfma_f32_16x16x32_bf16(pa1A, bL3, acc1A[3], 0,0,0);
  acc2A[0] = __builtin_amdgcn_mfma_f32_16x16x32_bf16(pa2A, bR0, acc2A[0], 0,0,0);
  acc2A[1] = __builtin_amdgcn_mfma_f32_16x16x32_bf16(pa2A, bR1, acc2A[1], 0,0,0);
  acc2A[2] = __builtin_amdgcn_mfma_f32_16x16x32_bf16(pa2A, bR2, acc2A[2], 0,0,0);
  acc2A[3] = __builtin_amdgcn_mfma_f32_16x16x32_bf16(pa2A, bR3, acc2A[3], 0,0,0);
  acc1B[0] = __builtin_amdgcn_mfma_f32_16x16x32_bf16(pa1B, bL0, acc1B[0], 0,0,0);
  acc1B[1] = __builtin_amdgcn_mfma_f32_16x16x32_bf16(pa1B, bL1, acc1B[1], 0,0,0);
  acc1B[2] = __builtin_amdgcn_mfma_f32_16x16x32_bf16(pa1B, bL2, acc1B[2], 0,0,0);
  acc1B[3] = __builtin_amdgcn_mfma_f32_16x16x32_bf16(pa1B, bL3, acc1B[3], 0,0,0);
  acc2B[0] = __builtin_amdgcn_mfma_f32_16x16x32_bf16(pa2B, bR0, acc2B[0], 0,0,0);
  acc2B[1] = __builtin_amdgcn_mfma_f32_16x16x32_bf16(pa2B, bR1, acc2B[1], 0,0,0);
  acc2B[2] = __builtin_amdgcn_mfma_f32_16x16x32_bf16(pa2B, bR2, acc2B[2], 0,0,0);
  acc2B[3] = __builtin_amdgcn_mfma_f32_16x16x32_bf16(pa2B, bR3, acc2B[3], 0,0,0);
}

#define ATTN_LOAD(S, n0) \
  fa00##S = *(const bf16x8*)&XLt[(size_t)((n0)+pr  )*CH +      8*g]; \
  fa01##S = *(const bf16x8*)&XLt[(size_t)((n0)+pr  )*CH + 32 + 8*g]; \
  fa10##S = *(const bf16x8*)&XLt[(size_t)((n0)+pr+4)*CH +      8*g]; \
  fa11##S = *(const bf16x8*)&XLt[(size_t)((n0)+pr+4)*CH + 32 + 8*g]; \
  bL0##S = *(const bf16x8*)&XLc[(size_t)( 0+lo)*HW + (n0) + 8*g];    \
  bL1##S = *(const bf16x8*)&XLc[(size_t)(16+lo)*HW + (n0) + 8*g];    \
  bL2##S = *(const bf16x8*)&XLc[(size_t)(32+lo)*HW + (n0) + 8*g];    \
  bL3##S = *(const bf16x8*)&XLc[(size_t)(48+lo)*HW + (n0) + 8*g];    \
  bR0##S = *(const bf16x8*)&XRc[(size_t)( 0+lo)*HW + (n0) + 8*g];    \
  bR1##S = *(const bf16x8*)&XRc[(size_t)(16+lo)*HW + (n0) + 8*g];    \
  bR2##S = *(const bf16x8*)&XRc[(size_t)(32+lo)*HW + (n0) + 8*g];    \
  bR3##S = *(const bf16x8*)&XRc[(size_t)(48+lo)*HW + (n0) + 8*g];    \
  r20##S = *(const f32x4*)&rs2[(n0) + 8*g];                          \
  r21##S = *(const f32x4*)&rs2[(n0) + 8*g + 4];

// ---------------- K3: fused aff->P -> b1^T/b2^T; 32 m/block, reg double-buffer ----------------
// grid (72, 8): block = 32-m tile; wave wv = n-quarter (18 steps of 32 n)
__global__ __launch_bounds__(256, 2) void k_attn(char* ws)
{
  __shared__ float red[4][64][17];
  __shared__ float s1part[4][32];
  __shared__ float rs1inv[32];
  int b    = blockIdx.y;
  int lane = threadIdx.x & 63;
  int wv   = __builtin_amdgcn_readfirstlane(threadIdx.x >> 6);
  int lo = lane & 15, g = lane >> 4;
  int m0 = blockIdx.x * 32;

  const u16* XLt = (const u16*)(ws + OFF_XLT) + (size_t)b*HW*CH;
  const u16* XRt = (const u16*)(ws + OFF_XRT) + (size_t)b*HW*CH;
  const u16* XLc = (const u16*)(ws + OFF_XLC) + (size_t)b*CH*HW;
  const u16* XRc = (const u16*)(ws + OFF_XRC) + (size_t)b*CH*HW;
  const float* rs2 = (const float*)(ws + OFF_RS2) + b*HW;

  bf16x8 fmA0 = *(const bf16x8*)&XRt[(size_t)(m0+lo)*CH + 8*g];
  bf16x8 fmA1 = *(const bf16x8*)&XRt[(size_t)(m0+lo)*CH + 32 + 8*g];
  bf16x8 fmB0 = *(const bf16x8*)&XRt[(size_t)(m0+16+lo)*CH + 8*g];
  bf16x8 fmB1 = *(const bf16x8*)&XRt[(size_t)(m0+16+lo)*CH + 32 + 8*g];

  int pr = ((lo >> 2) << 3) + (lo & 3);

  f32x4 acc1A[4], acc2A[4], acc1B[4], acc2B[4];
  #pragma unroll
  for (int ct=0;ct<4;ct++){
    f32x4 z4 = {0.f,0.f,0.f,0.f};
    acc1A[ct]=z4; acc2A[ct]=z4; acc1B[ct]=z4; acc2B[ct]=z4;
  }
  float s1A = 0.f, s1B = 0.f;

  int nbeg = wv * (HW/4);
  bf16x8 fa00X, fa01X, fa10X, fa11X, bL0X, bL1X, bL2X, bL3X, bR0X, bR1X, bR2X, bR3X;
  bf16x8 fa00Y, fa01Y, fa10Y, fa11Y, bL0Y, bL1Y, bL2Y, bL3Y, bR0Y, bR1Y, bR2Y, bR3Y;
  f32x4 r20X, r21X, r20Y, r21Y;

  ATTN_LOAD(X, nbeg)
  for (int s = 0; s < 18; s += 2){
    int n1 = nbeg + (s+1)*32;
    ATTN_LOAD(Y, n1)
    attn_compute(fa00X,fa01X,fa10X,fa11X, bL0X,bL1X,bL2X,bL3X, bR0X,bR1X,bR2X,bR3X,
                 r20X,r21X, fmA0,fmA1,fmB0,fmB1, acc1A,acc2A,acc1B,acc2B, s1A,s1B);
    int n2 = nbeg + ((s+2 < 18) ? (s+2)*32 : 0);
    ATTN_LOAD(X, n2)
    attn_compute(fa00Y,fa01Y,fa10Y,fa11Y, bL0Y,bL1Y,bL2Y,bL3Y, bR0Y,bR1Y,bR2Y,bR3Y,
                 r20Y,r21Y, fmA0,fmA1,fmB0,fmB1, acc1A,acc2A,acc1B,acc2B, s1A,s1B);
  }

  // ---- S1 block reduction ----
  s1A += __shfl_xor(s1A, 16, 64);  s1A += __shfl_xor(s1A, 32, 64);
  s1B += __shfl_xor(s1B, 16, 64);  s1B += __shfl_xor(s1B, 32, 64);
  if (lane < 16){ s1part[wv][lane] = s1A; s1part[wv][16+lane] = s1B; }
  __syncthreads();
  if (threadIdx.x < 32){
    int t = threadIdx.x;
    float s = s1part[0][t] + s1part[1][t] + s1part[2][t] + s1part[3][t];
    rs1inv[t] = 1.0f / s;
  }
  __syncthreads();

  float* B1 = (float*)(ws + OFF_B1) + (size_t)b*CH*HW;
  float* B2 = (float*)(ws + OFF_B2) + (size_t)b*CH*HW;
  int rl = threadIdx.x & 63;
  int rv = threadIdx.x >> 6;

  // 4 reduce phases: acc1A (scaled by rs1), acc2A, acc1B (scaled), acc2B
  #pragma unroll
  for (int v=0; v<16; ++v) red[wv][lane][v] = acc1A[v>>2][v&3];
  __syncthreads();
  #pragma unroll
  for (int k=0;k<4;k++){
    int v = rv + 4*k;
    float s = red[0][rl][v] + red[1][rl][v] + red[2][rl][v] + red[3][rl][v];
    int midx = ((rl>>4)<<2) + (v&3);
    int c = ((v>>2)<<4) + (rl & 15);
    B1[(size_t)c*HW + m0 + midx] = s * rs1inv[midx];
  }
  __syncthreads();
  #pragma unroll
  for (int v=0; v<16; ++v) red[wv][lane][v] = acc2A[v>>2][v&3];
  __syncthreads();
  #pragma unroll
  for (int k=0;k<4;k++){
    int v = rv + 4*k;
    float s = red[0][rl][v] + red[1][rl][v] + red[2][rl][v] + red[3][rl][v];
    int midx = ((rl>>4)<<2) + (v&3);
    int c = ((v>>2)<<4) + (rl & 15);
    B2[(size_t)c*HW + m0 + midx] = s;
  }
  __syncthreads();
  #pragma unroll
  for (int v=0; v<16; ++v) red[wv][lane][v] = acc1B[v>>2][v&3];
  __syncthreads();
  #pragma unroll
  for (int k=0;k<4;k++){
    int v = rv + 4*k;
    float s = red[0][rl][v] + red[1][rl][v] + red[2][rl][v] + red[3][rl][v];
    int midx = ((rl>>4)<<2) + (v&3);
    int c = ((v>>2)<<4) + (rl & 15);
    B1[(size_t)c*HW + m0 + 16 + midx] = s * rs1inv[16 + midx];
  }
  __syncthreads();
  #pragma unroll
  for (int v=0; v<16; ++v) red[wv][lane][v] = acc2B[v>>2][v&3];
  __syncthreads();
  #pragma unroll
  for (int k=0;k<4;k++){
    int v = rv + 4*k;
    float s = red[0][rl][v] + red[1][rl][v] + red[2][rl][v] + red[3][rl][v];
    int midx = ((rl>>4)<<2) + (v&3);
    int c = ((v>>2)<<4) + (rl & 15);
    B2[(size_t)c*HW + m0 + 16 + midx] = s;
  }
}

// ---------------- K4: gate + output convs (raw f32 weights), f32 OUTPUT ----------------
// grid (36, 2, 8): p-tile of 64, side, batch
__global__ __launch_bounds__(256) void k_out(
    char* ws,
    const float* gwL, const float* gbL, const float* gwR, const float* gbR,
    const float* wLo, const float* bLoi, const float* wRo, const float* bRoi,
    float* out)
{
  __shared__ float xT[64][64];
  __shared__ float bT[64][64];
  __shared__ float gpart[4][64];
  __shared__ float gLds[64];
  int t = threadIdx.x;
  int p0 = blockIdx.x*64;
  int side = blockIdx.y;
  int b = blockIdx.z;
  const float* braw = (const float*)(ws + (side ? OFF_B2 : OFF_B1)) + (size_t)b*CH*HW;
  const u16*   xc   = (const u16*)(ws + (side ? OFF_XRC : OFF_XLC)) + (size_t)b*CH*HW;
  const float* w    = side ? wRo : wLo;
  const float* gw   = side ? gwR : gwL;
  float        gb   = side ? gbR[0] : gbL[0];
  const float* bias = side ? bRoi : bLoi;

  #pragma unroll
  for (int i=0;i<16;i++){
    int flat = i*256 + t;
    int c = flat >> 6, pl = flat & 63;
    bT[c][pl] = braw[(size_t)c*HW + p0 + pl];
    xT[c][pl] = bf2f(xc[(size_t)c*HW + p0 + pl]);
  }
  __syncthreads();
  {
    int q = t >> 6, pl = t & 63;
    float a = 0.f;
    #pragma unroll
    for (int c = 0; c < 16; c++) a = fmaf(gw[16*q + c], bT[16*q + c][pl], a);
    gpart[q][pl] = a;
  }
  __syncthreads();
  if (t < 64){
    float x = gpart[0][t]+gpart[1][t]+gpart[2][t]+gpart[3][t] + gb;
    gLds[t] = 1.0f/(1.0f + exp2f(-x*L2E));    // sigmoid
  }
  __syncthreads();
  #pragma unroll
  for (int i=0;i<16;i++){
    int flat = i*256 + t;
    int c = flat >> 6, pl = flat & 63;
    bT[c][pl] *= gLds[pl];
  }
  __syncthreads();
  int wv = t >> 6;
  int lane = t & 63;
  float* outp = out + ((size_t)side*B_ + b)*CH*HW;
  for (int oi=0; oi<16; oi++){
    int o = wv*16 + oi;
    float a = bias[o];
    #pragma unroll 8
    for (int c=0;c<64;c++){
      a = fmaf(w[o*128 + c],      xT[c][lane], a);
      a = fmaf(w[o*128 + 64 + c], bT[c][lane], a);
    }
    outp[(size_t)o*HW + p0 + lane] = a;
  }
}

extern "C" void kernel_launch(void* const* d_in, const int* in_sizes, int n_in,
                              void* d_out, int out_size, void* d_ws, size_t ws_size,
                              hipStream_t stream)
{
  char* ws = (char*)d_ws;
  k_proj <<<dim3(9,2,16), 256, 0, stream>>>(
      (const float*)d_in[0], (const float*)d_in[1],
      (const float*)d_in[2], (const float*)d_in[3],
      (const float*)d_in[4], (const float*)d_in[5],
      (const float*)d_in[6], (const float*)d_in[7], ws);
  k_stats<<<dim3(72,8), 256, 0, stream>>>(ws);
  k_attn <<<dim3(72,8), 256, 0, stream>>>(ws);
  k_out  <<<dim3(36,2,8), 256, 0, stream>>>(
      ws,
      (const float*)d_in[8],  (const float*)d_in[9],
      (const float*)d_in[10], (const float*)d_in[11],
      (const float*)d_in[12], (const float*)d_in[13],
      (const float*)d_in[14], (const float*)d_in[15],
      (float*)d_out);
}